// Round 15
// baseline (801.672 us; speedup 1.0000x reference)
//
#include <hip/hip_runtime.h>
#include <stdint.h>

#define BATCH 8192
#define DIM   1024            // elements per row; fp8 => also bytes per row
#define NTILE 64              // 8192 / 128 tiles per dimension
#define MAXB  292             // max tiles per XCD band
#define GRIDX (8 * MAXB)      // virtual sim grid per feature; pads skip
#define PBLK  768             // persistent blocks = 3 per CU.  DEADLOCK-PROOF:
                              // LDS 32KB -> 5 blk/CU, thr -> 8, VGPR cap 84
                              // (launch_bounds(256,3), r7/r10-measured) -> >=3
                              // waves/SIMD => all 768 blocks co-resident.

#define FSZ   ((size_t)BATCH * DIM)   // bytes per feature in Fn (8 MB)
#define PAN   ((size_t)64 * 8192)     // bytes per K-block panel (1 MB)
#define OPB   8192                    // bytes per operand tile image
#define SBUF  8192                    // bytes per LDS tile buffer

#define FSCALE 8.0f                          // pre-scale before fp8 quant
#define EXPF   (2.0f / (FSCALE * FSCALE))    // exp(2*dot) = exp(acc * EXPF)

typedef int   intx4   __attribute__((ext_vector_type(4)));
typedef float floatx4 __attribute__((ext_vector_type(4)));
typedef long  longx2  __attribute__((ext_vector_type(2)));

__device__ __forceinline__ void async_ld16(const void* g, void* l) {
    __builtin_amdgcn_global_load_lds(
        (__attribute__((address_space(1))) void*)(void*)g,
        (__attribute__((address_space(3))) void*)l,
        16, 0, 0);
}

__device__ __forceinline__ longx2 as_l2(intx4 v) {
    longx2 r;
    __builtin_memcpy(&r, &v, 16);
    return r;
}

__device__ __forceinline__ float dot4(float4 v) {
    return v.x * v.x + v.y * v.y + v.z * v.z + v.w * v.w;
}

__device__ __forceinline__ int pk8(float4 v, float inv) {
    int p = __builtin_amdgcn_cvt_pk_fp8_f32(v.x * inv, v.y * inv, 0, false);
    return  __builtin_amdgcn_cvt_pk_fp8_f32(v.z * inv, v.w * inv, p, true);
}

// software grid barrier: arrive (release) + tid0 spin (acquire) + agent fences.
// __threadfence() on gfx950 = agent-scope acq_rel -> L1/L2 wb+inv, which gives
// cross-XCD visibility of Fn/P written before the barrier.
__device__ __forceinline__ void gridbar(unsigned* bar, unsigned expected) {
    __syncthreads();
    __threadfence();                                    // release side
    if (threadIdx.x == 0) {
        __hip_atomic_fetch_add(bar, 1u, __ATOMIC_RELEASE, __HIP_MEMORY_SCOPE_AGENT);
        unsigned v;
        do {
            __builtin_amdgcn_s_sleep(8);
            v = __hip_atomic_load(bar, __ATOMIC_ACQUIRE, __HIP_MEMORY_SCOPE_AGENT);
        } while (v < expected);
    }
    __syncthreads();
    __threadfence();                                    // acquire side (inv stale)
}

// =================== single fused kernel (normal launch) ===================
// ROUND-15: r13/r14's identical absmax 2.77 == the full reference value ->
// out was never written: hipLaunchCooperativeKernel silently fails under the
// harness's graph capture (only the memset ran). Same fusion, plain <<<>>>
// launch + software grid barrier (counters in ws, memset per launch).
// Theory under test (unchanged): the invariant ~90-us non-sim gap across 5
// norm rewrites (roofline ~13 us) is inter-dispatch overhead; one dispatch
// removes it. Phase 2 is round-9's proven sim body (126 us, 0 conflicts)
// over virtual blocks (768 % 8 == 0 preserves XCD banding), with a vmcnt(0)
// drain at each virtual-tile top so the counted vmcnt(4) never mixes the
// previous epilogue's stores with this tile's staging loads.
__global__ __launch_bounds__(256, 3) void fused_kernel(const float* __restrict__ text,
                                                       const float* __restrict__ image,
                                                       const int* __restrict__ label,
                                                       unsigned char* __restrict__ Fn,
                                                       float* __restrict__ P,
                                                       unsigned* __restrict__ bar,
                                                       float* __restrict__ out) {
    __shared__ __align__(16) unsigned char As[2][SBUF];
    __shared__ __align__(16) unsigned char Bs[2][SBUF];

    const int b   = blockIdx.x;
    const int tid = threadIdx.x;

    // ---------------- phase 1: row L2-normalize fp32 -> fp8 e4m3 ----------------
    // Frag-packed layout (round-6/9, byte-identical):
    //   Fn[f][kb:16][rowblk:64][g:8][q:4][cl:16][16 B]
    // Two-pass (ss, then re-read+quant) keeps VGPR under the 84 cap.
    {
        const int r32 = tid >> 3;             // row within 32-row group
        const int sub = tid & 7;              // 8 threads per row
        const int q   = sub & 3;
        const int kb0 = sub >> 2;
        for (int g = b; g < 512; g += PBLK) { // 512 groups = 2 features x 256
            const int f   = g >> 8;
            const int x32 = g & 255;
            const float* in = f ? image : text;
            const int row = x32 * 32 + r32;
            const float4* src = (const float4*)(in + (size_t)row * DIM);
            float ss = 0.f;
            #pragma unroll
            for (int s = 0; s < 8; ++s) {     // pass 1: sum of squares only
                const int fb = (kb0 + 2 * s) * 16 + 2 * q;
                ss += dot4(src[fb]) + dot4(src[fb + 1])
                    + dot4(src[fb + 8]) + dot4(src[fb + 9]);
            }
            ss += __shfl_xor(ss, 1); ss += __shfl_xor(ss, 2); ss += __shfl_xor(ss, 4);
            const float inv = FSCALE / fmaxf(sqrtf(ss), 1e-12f);

            const int rb = row >> 7;
            const int gg = (row & 127) >> 4;
            const int cl = row & 15;
            unsigned char* obase = Fn + (size_t)f * FSZ + (size_t)rb * OPB
                                 + gg * 1024 + q * 256 + cl * 16;
            #pragma unroll
            for (int s = 0; s < 8; ++s) {     // pass 2: re-read (L1/L2 hot) + quant
                const int fb = (kb0 + 2 * s) * 16 + 2 * q;
                intx4 w;
                w[0] = pk8(src[fb],     inv);
                w[1] = pk8(src[fb + 1], inv);
                w[2] = pk8(src[fb + 8], inv);
                w[3] = pk8(src[fb + 9], inv);
                *(intx4*)(obase + (size_t)(kb0 + 2 * s) * PAN) = w;   // 16-B chunk
            }
        }
    }
    gridbar(bar + 0, PBLK);

    // ---------------- phase 2: fused symmetric sim GEMM + exp + dual sum --------
    // Round-9 body (fp8 16x16x32 MFMA, BK=64, dbuf, counted vmcnt, frag-packed
    // linear LDS, no atomics; slot bj row-parts / bi col-parts).
    {
        const int bs_[8] = {0, 23, 32, 40, 46, 51, 56, 60};
        const int be_[8] = {23, 32, 40, 46, 51, 56, 60, 64};
        const int bn_[8] = {276, 252, 292, 261, 245, 270, 234, 250};

        const int lane = tid & 63;
        const int wave = tid >> 6;
        const int wm   = wave >> 1;
        const int wn   = wave & 1;
        const int quad = lane >> 4;
        const int cl   = lane & 15;

        unsigned char* lA = As[0] + wave * 2048 + lane * 16;
        unsigned char* lB = Bs[0] + wave * 2048 + lane * 16;
        const unsigned char* aF = As[0] + quad * 256 + cl * 16;
        const unsigned char* bF = Bs[0] + quad * 256 + cl * 16;

        for (int v = b; v < 2 * GRIDX; v += PBLK) {
            __syncthreads();                  // LDS reuse guard across iterations
            // drain outstanding VMEM (previous tile's epilogue stores) so the
            // counted vmcnt(4) below counts ONLY this tile's staging loads.
            asm volatile("s_waitcnt vmcnt(0)" ::: "memory");

            const int vx = v % GRIDX;         // 768 % 8 == 0 -> band preserved
            const int f  = v / GRIDX;
            const int x  = vx & 7;
            const int l0 = vx >> 3;
            if (l0 >= bn_[x]) continue;       // padding slot

            const int s_ = bs_[x];
            const int w_ = be_[x] - s_;
            int bi, bj;
            const int nfull = s_ * w_;
            if (l0 < nfull) {
                bi = l0 / w_;
                bj = s_ + (l0 % w_);
            } else {
                int l2 = l0 - nfull;
                int k = 0, width = w_;
                while (l2 >= width) { l2 -= width; --width; ++k; }
                bi = s_ + k;
                bj = bi + l2;
            }
            const bool diag = (bi == bj);
            const int rowTile = bi * 128;
            const int colTile = bj * 128;

            const unsigned char* gA = Fn + (size_t)f * FSZ + (size_t)bi * OPB + wave * 2048 + lane * 16;
            const unsigned char* gB = Fn + (size_t)f * FSZ + (size_t)bj * OPB + wave * 2048 + lane * 16;

            floatx4 acc[4][4];
            const floatx4 z4 = {0.f, 0.f, 0.f, 0.f};
            #pragma unroll
            for (int mi = 0; mi < 4; ++mi)
                #pragma unroll
                for (int ni = 0; ni < 4; ++ni) acc[mi][ni] = z4;

            // prologue: stage kb 0 into buffer 0
            #pragma unroll
            for (int t = 0; t < 2; ++t) {
                async_ld16(gA + (size_t)t * 1024, lA + t * 1024);
                async_ld16(gB + (size_t)t * 1024, lB + t * 1024);
            }
            gA += PAN; gB += PAN;

            #pragma unroll
            for (int kb = 0; kb < 16; ++kb) {
                const int cur = kb & 1;
                const int nxt = cur ^ 1;
                if (kb < 15) {
                    #pragma unroll
                    for (int t = 0; t < 2; ++t) {
                        async_ld16(gA + (size_t)t * 1024, lA + nxt * SBUF + t * 1024);
                        async_ld16(gB + (size_t)t * 1024, lB + nxt * SBUF + t * 1024);
                    }
                    gA += PAN; gB += PAN;
                    asm volatile("s_waitcnt vmcnt(4)" ::: "memory");
                } else {
                    asm volatile("s_waitcnt vmcnt(0)" ::: "memory");
                }
                __builtin_amdgcn_s_barrier();
                __builtin_amdgcn_sched_barrier(0);

                longx2 bfr[4];
                #pragma unroll
                for (int ni = 0; ni < 4; ++ni)
                    bfr[ni] = as_l2(*(const intx4*)(bF + cur * SBUF + (wn * 4 + ni) * 1024));
                __builtin_amdgcn_s_setprio(1);
                #pragma unroll
                for (int mi = 0; mi < 4; ++mi) {
                    longx2 afr = as_l2(*(const intx4*)(aF + cur * SBUF + (wm * 4 + mi) * 1024));
                    #pragma unroll
                    for (int ni = 0; ni < 4; ++ni) {
                        acc[mi][ni] = __builtin_amdgcn_mfma_f32_16x16x32_fp8_fp8(
                            afr[0], bfr[ni][0], acc[mi][ni], 0, 0, 0);
                        acc[mi][ni] = __builtin_amdgcn_mfma_f32_16x16x32_fp8_fp8(
                            afr[1], bfr[ni][1], acc[mi][ni], 0, 0, 0);
                    }
                }
                __builtin_amdgcn_s_setprio(0);
                __builtin_amdgcn_sched_barrier(0);
                __builtin_amdgcn_s_barrier();
            }

            // epilogue: exp, eye mask, LDS reduction, partial stores (no atomics)
            __syncthreads();
            float* red = (float*)As;

            int   colg[4], colLoc[4];
            float wRc[4];
            #pragma unroll
            for (int ni = 0; ni < 4; ++ni) {
                colLoc[ni] = wn * 64 + ni * 16 + cl;
                colg[ni]   = colTile + colLoc[ni];
                wRc[ni]    = (label[colg[ni]] != 0) ? 1.0f : 0.0f;
            }

            float colR[4] = {0.f, 0.f, 0.f, 0.f};
            float colN[4] = {0.f, 0.f, 0.f, 0.f};

            #pragma unroll
            for (int mi = 0; mi < 4; ++mi) {
                const int rowLocB = wm * 64 + mi * 16 + quad * 4;   // C/D: row=quad*4+reg
                #pragma unroll
                for (int r = 0; r < 4; ++r) {
                    const int rowLoc = rowLocB + r;
                    const int rowg   = rowTile + rowLoc;
                    const float wRr  = (label[rowg] != 0) ? 1.0f : 0.0f;
                    float pR = 0.f, pN = 0.f;
                    #pragma unroll
                    for (int ni = 0; ni < 4; ++ni) {
                        float c = acc[mi][ni][r];
                        float e = __expf(c * EXPF);
                        if (diag) e = (rowg == colg[ni]) ? 0.0f : e;
                        pR += wRc[ni] * e;
                        pN += (1.0f - wRc[ni]) * e;
                        colR[ni] += wRr * e;
                        colN[ni] += (1.0f - wRr) * e;
                    }
                    #pragma unroll
                    for (int m = 1; m < 16; m <<= 1) {
                        pR += __shfl_xor(pR, m);
                        pN += __shfl_xor(pN, m);
                    }
                    if (cl == 0) {
                        red[wn * 128 + rowLoc]       = pR;
                        red[256 + wn * 128 + rowLoc] = pN;
                    }
                }
            }

            if (!diag) {
                #pragma unroll
                for (int ni = 0; ni < 4; ++ni) {
                    float cR = colR[ni], cN = colN[ni];
                    cR += __shfl_xor(cR, 16); cN += __shfl_xor(cN, 16);
                    cR += __shfl_xor(cR, 32); cN += __shfl_xor(cN, 32);
                    if (quad == 0) {
                        red[512 + wm * 128 + colLoc[ni]] = cR;
                        red[768 + wm * 128 + colLoc[ni]] = cN;
                    }
                }
            }

            __syncthreads();
            float* Pr = P + ((size_t)f * 2 + 0) * (size_t)NTILE * BATCH;
            float* Pn = P + ((size_t)f * 2 + 1) * (size_t)NTILE * BATCH;
            if (tid < 128) {
                Pr[(size_t)bj * BATCH + rowTile + tid] = red[tid]       + red[128 + tid];
                Pn[(size_t)bj * BATCH + rowTile + tid] = red[256 + tid] + red[384 + tid];
                if (!diag) {
                    Pr[(size_t)bi * BATCH + colTile + tid] = red[512 + tid] + red[640 + tid];
                    Pn[(size_t)bi * BATCH + colTile + tid] = red[768 + tid] + red[896 + tid];
                }
            }
        }
    }
    gridbar(bar + 1, PBLK);

    // ---------------- phase 3: partial reduce + per-row loss + global reduce ----
    if (b < 64) {
        const int idx = b * 256 + tid;        // 0..16383 = (f, i)
        const int f = idx >> 13;
        const int i = idx & (BATCH - 1);
        const int lab = label[i];
        const float* Pr = P + ((size_t)f * 2 + 0) * (size_t)NTILE * BATCH;
        const float* Pn = Pr + (size_t)NTILE * BATCH;
        float sR = 0.f, sN = 0.f;
        #pragma unroll 8
        for (int s = 0; s < NTILE; ++s) {
            sR += Pr[(size_t)s * BATCH + i];
            sN += Pn[(size_t)s * BATCH + i];
        }
        const float own = lab ? sR : sN;
        const float oth = lab ? sN : sR;
        float t = -logf(own / (own + oth) + 1e-8f) * (1.0f / 4096.0f);
        #pragma unroll
        for (int m = 32; m >= 1; m >>= 1) t += __shfl_xor(t, m);
        float* lred = (float*)As;             // reuse (barrier passed)
        if ((tid & 63) == 0) lred[tid >> 6] = t;
        __syncthreads();
        if (tid == 0) atomicAdd(out, lred[0] + lred[1] + lred[2] + lred[3]);
    }
}

extern "C" void kernel_launch(void* const* d_in, const int* in_sizes, int n_in,
                              void* d_out, int out_size, void* d_ws, size_t ws_size,
                              hipStream_t stream) {
    const float* text  = (const float*)d_in[0];
    const float* image = (const float*)d_in[1];
    const int*   label = (const int*)d_in[2];
    float* out = (float*)d_out;

    // workspace: Fn[16 MB] fp8, P[16 MB] f32, then barrier counters
    unsigned char* Fn = (unsigned char*)d_ws;
    float* P = (float*)((char*)d_ws + (size_t)2 * BATCH * DIM);
    unsigned* bar = (unsigned*)((char*)d_ws + (size_t)2 * BATCH * DIM
                                + (size_t)2 * 2 * NTILE * BATCH * sizeof(float));

    hipMemsetAsync(out, 0, sizeof(float), stream);
    hipMemsetAsync(bar, 0, 2 * sizeof(unsigned), stream);

    fused_kernel<<<dim3(PBLK), dim3(256), 0, stream>>>(text, image, label,
                                                       Fn, P, bar, out);
}